// Round 1
// baseline (107.209 us; speedup 1.0000x reference)
//
#include <hip/hip_runtime.h>

#define B_SZ 1024
#define F_SZ 512
#define NK   50
#define KD   5
#define C_SZ 250            // NK*KD
#define OUTW 562            // F_SZ + NK
#define WSTR 8              // padded KD stride in ws2
#define WS2_ELEMS (NK * B_SZ * WSTR)   // 409600 floats = 1.6 MB
#define LOG2E 1.44269504088896340736f

// ---------------------------------------------------------------------------
// Kernel 1: copy x into out, zero the 50 feature columns, zero ws2 (M accum).
// grid 1024 (one block per row), 256 threads.
// ---------------------------------------------------------------------------
__global__ __launch_bounds__(256) void prep_kernel(const float* __restrict__ x,
                                                   float* __restrict__ out,
                                                   float* __restrict__ ws2) {
    const int row = blockIdx.x;
    const int t   = threadIdx.x;
    out[row * OUTW + t]       = x[row * F_SZ + t];
    out[row * OUTW + 256 + t] = x[row * F_SZ + 256 + t];
    if (t < NK) out[row * OUTW + F_SZ + t] = 0.0f;

    const int gid = row * 256 + t;              // 262144 threads total
    if (gid < WS2_ELEMS / 2) {
        ((float2*)ws2)[gid] = make_float2(0.0f, 0.0f);
    }
}

// ---------------------------------------------------------------------------
// Kernel 2: M = x @ T (fp32 vector GEMM), scaled by log2(e), atomicAdd into
// ws2 laid out as [NK][B][WSTR] (d<5 valid, cols 5..7 stay zero).
// grid 256 = 32 row-tiles (32 rows) x 8 K-splits (64 f each); 256 threads.
// Wave w handles rows rt*32 + w*8 .. +8; lane owns 4 columns (lane + 64*j).
// x is wave-uniform -> scalar loads (SMEM pipe); T coalesced vector loads.
// ---------------------------------------------------------------------------
__global__ __launch_bounds__(256) void gemm_kernel(const float* __restrict__ x,
                                                   const float* __restrict__ T,
                                                   float* __restrict__ ws2) {
    const int rt   = blockIdx.x & 31;   // row tile
    const int fs   = blockIdx.x >> 5;   // f split
    const int w    = __builtin_amdgcn_readfirstlane(threadIdx.x >> 6);
    const int lane = threadIdx.x & 63;
    const int r0   = rt * 32 + w * 8;
    const int f0   = fs * 64;

    int c[4], cc[4];
#pragma unroll
    for (int j = 0; j < 4; ++j) {
        c[j]  = lane + 64 * j;
        cc[j] = (c[j] < C_SZ) ? c[j] : (C_SZ - 1);   // clamp keeps loads in-bounds
    }

    float acc[8][4];
#pragma unroll
    for (int r = 0; r < 8; ++r)
#pragma unroll
        for (int j = 0; j < 4; ++j) acc[r][j] = 0.0f;

#pragma unroll 4
    for (int ff = 0; ff < 64; ++ff) {
        const int f = f0 + ff;
        float tv0 = T[f * C_SZ + cc[0]];
        float tv1 = T[f * C_SZ + cc[1]];
        float tv2 = T[f * C_SZ + cc[2]];
        float tv3 = T[f * C_SZ + cc[3]];
#pragma unroll
        for (int r = 0; r < 8; ++r) {
            const float xv = x[(r0 + r) * F_SZ + f];   // uniform -> s_load
            acc[r][0] += xv * tv0;
            acc[r][1] += xv * tv1;
            acc[r][2] += xv * tv2;
            acc[r][3] += xv * tv3;
        }
    }

#pragma unroll
    for (int j = 0; j < 4; ++j) {
        if (c[j] < C_SZ) {
            const int k = c[j] / KD;
            const int d = c[j] % KD;
            float* dst = ws2 + k * (B_SZ * WSTR) + d;
#pragma unroll
            for (int r = 0; r < 8; ++r)
                atomicAdd(dst + (r0 + r) * WSTR, acc[r][j] * LOG2E);
        }
    }
}

// ---------------------------------------------------------------------------
// Kernel 3: minibatch features. grid 800 = 50 k x 16 j-splits; 256 threads.
// Thread t owns rows i = t + 256*r (r=0..3). j-tile (64 rows) staged in LDS;
// all lanes read the same j -> pure broadcast, zero bank conflicts.
// Per pair: 5 subs + abs-folded adds + one v_exp_f32 (neg modifier free).
// 16 atomicAdd partials per output (out features pre-zeroed by prep).
// ---------------------------------------------------------------------------
__global__ __launch_bounds__(256) void pair_kernel(const float* __restrict__ ws2,
                                                   float* __restrict__ out) {
    const int k  = blockIdx.x >> 4;
    const int js = blockIdx.x & 15;
    const int j0 = js * 64;
    const int t  = threadIdx.x;

    __shared__ float q_lds[64 * WSTR];   // 2 KB

    const float* mk = ws2 + k * (B_SZ * WSTR);
    if (t < 128) {
        ((float4*)q_lds)[t] = ((const float4*)(mk + j0 * WSTR))[t];
    }
    __syncthreads();

    float m[4][5];
#pragma unroll
    for (int r = 0; r < 4; ++r) {
        const float* mp = mk + (t + 256 * r) * WSTR;
        const float4 a = *(const float4*)mp;
        m[r][0] = a.x; m[r][1] = a.y; m[r][2] = a.z; m[r][3] = a.w;
        m[r][4] = mp[4];
    }

    float acc[4] = {0.0f, 0.0f, 0.0f, 0.0f};
#pragma unroll 2
    for (int jj = 0; jj < 64; ++jj) {
        const float4 qa = *(const float4*)&q_lds[jj * WSTR];
        const float  q4 = q_lds[jj * WSTR + 4];
#pragma unroll
        for (int r = 0; r < 4; ++r) {
            const float s = fabsf(m[r][0] - qa.x) + fabsf(m[r][1] - qa.y)
                          + fabsf(m[r][2] - qa.z) + fabsf(m[r][3] - qa.w)
                          + fabsf(m[r][4] - q4);
            acc[r] += __builtin_amdgcn_exp2f(-s);
        }
    }

#pragma unroll
    for (int r = 0; r < 4; ++r)
        atomicAdd(&out[(t + 256 * r) * OUTW + F_SZ + k], acc[r]);
}

// ---------------------------------------------------------------------------
extern "C" void kernel_launch(void* const* d_in, const int* in_sizes, int n_in,
                              void* d_out, int out_size, void* d_ws, size_t ws_size,
                              hipStream_t stream) {
    const float* x = (const float*)d_in[0];   // [1024, 512]
    const float* T = (const float*)d_in[1];   // [512, 250]
    float* out = (float*)d_out;               // [1024, 562]
    float* ws2 = (float*)d_ws;                // [50][1024][8] floats

    prep_kernel<<<1024, 256, 0, stream>>>(x, out, ws2);
    gemm_kernel<<<256, 256, 0, stream>>>(x, T, ws2);
    pair_kernel<<<800, 256, 0, stream>>>(ws2, out);
}

// Round 2
// 54.095 us; speedup vs baseline: 1.9819x; 1.9819x over previous
//
#include <hip/hip_runtime.h>

#define B_SZ 1024
#define F_SZ 512
#define NK   50
#define KD   5
#define C_SZ 250            // NK*KD
#define OUTW 562            // F_SZ + NK
#define WSTR 8              // padded KD stride in M planes
#define M_PLANE (NK * B_SZ * WSTR)     // 409600 floats = 1.6384 MB per k-split plane
#define JSPLIT 16
#define PART_ELEMS (NK * JSPLIT * B_SZ) // 819200 floats = 3.2768 MB
#define LOG2E 1.44269504088896340736f

// ---------------------------------------------------------------------------
// K1: copy x into out rows (512 fp32 each). If zero_feat, also zero the 50
// feature columns (atomic fallback modes only). grid 1024 x 128.
// ---------------------------------------------------------------------------
__global__ __launch_bounds__(128) void copy_kernel(const float* __restrict__ x,
                                                   float* __restrict__ out,
                                                   int zero_feat) {
    const int row = blockIdx.x;
    const int t   = threadIdx.x;
    const float2* xs = (const float2*)(x + row * F_SZ);
    float2*       od = (float2*)(out + row * OUTW);   // row*562*4B is 8B aligned
    od[t]       = xs[t];
    od[t + 128] = xs[t + 128];
    if (zero_feat && t < NK) out[row * OUTW + F_SZ + t] = 0.0f;
}

// ---------------------------------------------------------------------------
// K2: M = x @ T (fp32 vector), scaled by log2(e). NO atomics: each k-split
// writes its own plane ws2[ks][NK][B][WSTR]; pair_kernel sums the planes.
// grid = 128 row-tiles * KS; 256 threads; thread t owns column c=t (<250).
// x reads are block-uniform -> scalar loads; T reads coalesced.
// ---------------------------------------------------------------------------
template <int KS>
__global__ __launch_bounds__(256) void gemm_kernel(const float* __restrict__ x,
                                                   const float* __restrict__ T,
                                                   float* __restrict__ ws2) {
    constexpr int FLEN = F_SZ / KS;
    const int rt = blockIdx.x & 127;
    const int ks = blockIdx.x >> 7;
    const int t  = threadIdx.x;
    const int r0 = rt * 8;
    const int f0 = ks * FLEN;
    if (t >= C_SZ) return;                 // no __syncthreads below -> safe
    const int k = t / KD;
    const int d = t - KD * k;

    float acc[8] = {0.f, 0.f, 0.f, 0.f, 0.f, 0.f, 0.f, 0.f};
    const float* xp = x + r0 * F_SZ + f0;  // block-uniform base
    const float* Tp = T + (size_t)f0 * C_SZ + t;

#pragma unroll 8
    for (int f = 0; f < FLEN; ++f) {
        const float tv = Tp[(size_t)f * C_SZ];
#pragma unroll
        for (int r = 0; r < 8; ++r)
            acc[r] += xp[r * F_SZ + f] * tv;   // uniform -> s_load
    }

    float* dst = ws2 + (size_t)ks * M_PLANE + k * (B_SZ * WSTR) + d;
#pragma unroll
    for (int r = 0; r < 8; ++r)
        dst[(r0 + r) * WSTR] = acc[r] * LOG2E;
}

// ---------------------------------------------------------------------------
// K3: pairwise features. grid 800 = 50 k x 16 j-splits; 512 threads (8 waves,
// ~6.25 waves/SIMD machine-wide). Thread t owns rows i = t, t+512.
// j-tile (64 rows) staged in LDS with the KS plane-sum folded in.
// Fast path stores per-jsplit partials (no atomics); fallback atomics to out.
// ---------------------------------------------------------------------------
template <int KS, bool ATOMIC>
__global__ __launch_bounds__(512) void pair_kernel(const float* __restrict__ ws2,
                                                   float* __restrict__ dst) {
    const int k  = blockIdx.x >> 4;
    const int js = blockIdx.x & 15;
    const int j0 = js * 64;
    const int t  = threadIdx.x;

    __shared__ float q_lds[64 * WSTR];     // 2 KB

    const float* pa = ws2 + (size_t)k * (B_SZ * WSTR);
    const float* pb = pa + (size_t)M_PLANE;

    {   // stage j-tile (coalesced, 1 float/thread), summing KS planes
        float v = pa[j0 * WSTR + t];
        if (KS == 2) v += pb[j0 * WSTR + t];
        q_lds[t] = v;
    }

    float m[2][5];
#pragma unroll
    for (int r = 0; r < 2; ++r) {
        const int i = t + r * 512;
        float4 a = *(const float4*)&pa[i * WSTR];
        float  e = pa[i * WSTR + 4];
        if (KS == 2) {
            float4 b = *(const float4*)&pb[i * WSTR];
            a.x += b.x; a.y += b.y; a.z += b.z; a.w += b.w;
            e   += pb[i * WSTR + 4];
        }
        m[r][0] = a.x; m[r][1] = a.y; m[r][2] = a.z; m[r][3] = a.w; m[r][4] = e;
    }
    __syncthreads();

    float acc[2] = {0.0f, 0.0f};
#pragma unroll 4
    for (int jj = 0; jj < 64; ++jj) {
        const float4 qa = *(const float4*)&q_lds[jj * WSTR];
        const float  qe = q_lds[jj * WSTR + 4];
#pragma unroll
        for (int r = 0; r < 2; ++r) {
            const float s = fabsf(m[r][0] - qa.x) + fabsf(m[r][1] - qa.y)
                          + fabsf(m[r][2] - qa.z) + fabsf(m[r][3] - qa.w)
                          + fabsf(m[r][4] - qe);
            acc[r] += __builtin_amdgcn_exp2f(-s);
        }
    }

#pragma unroll
    for (int r = 0; r < 2; ++r) {
        const int i = t + r * 512;
        if (ATOMIC) {
            atomicAdd(&dst[(size_t)i * OUTW + F_SZ + k], acc[r]);
        } else {
            dst[(size_t)(k * JSPLIT + js) * B_SZ + i] = acc[r];
        }
    }
}

// ---------------------------------------------------------------------------
// K4: fold the 16 j-split partials into out. grid 200 x 256.
// ---------------------------------------------------------------------------
__global__ __launch_bounds__(256) void reduce_kernel(const float* __restrict__ part,
                                                     float* __restrict__ out) {
    const int k = blockIdx.x >> 2;
    const int i = ((blockIdx.x & 3) << 8) | threadIdx.x;
    float s = 0.0f;
#pragma unroll
    for (int sp = 0; sp < JSPLIT; ++sp)
        s += part[(size_t)(k * JSPLIT + sp) * B_SZ + i];   // coalesced across lanes
    out[(size_t)i * OUTW + F_SZ + k] = s;
}

// ---------------------------------------------------------------------------
extern "C" void kernel_launch(void* const* d_in, const int* in_sizes, int n_in,
                              void* d_out, int out_size, void* d_ws, size_t ws_size,
                              hipStream_t stream) {
    const float* x = (const float*)d_in[0];   // [1024, 512]
    const float* T = (const float*)d_in[1];   // [512, 250]
    float* out = (float*)d_out;               // [1024, 562]
    float* ws2 = (float*)d_ws;                // KS planes of [50][1024][8]
    float* part = ws2 + 2 * (size_t)M_PLANE;  // [50][16][1024]

    const size_t need_full   = (size_t)(2 * M_PLANE + PART_ELEMS) * 4;  // 6.55 MB
    const size_t need_2plane = (size_t)(2 * M_PLANE) * 4;               // 3.28 MB
    const int mode = (ws_size >= need_full) ? 2 : (ws_size >= need_2plane ? 1 : 0);

    copy_kernel<<<1024, 128, 0, stream>>>(x, out, mode == 2 ? 0 : 1);

    if (mode >= 1) {
        gemm_kernel<2><<<256, 256, 0, stream>>>(x, T, ws2);
    } else {
        gemm_kernel<1><<<128, 256, 0, stream>>>(x, T, ws2);
    }

    if (mode == 2) {
        pair_kernel<2, false><<<NK * JSPLIT, 512, 0, stream>>>(ws2, part);
        reduce_kernel<<<200, 256, 0, stream>>>(part, out);
    } else if (mode == 1) {
        pair_kernel<2, true><<<NK * JSPLIT, 512, 0, stream>>>(ws2, out);
    } else {
        pair_kernel<1, true><<<NK * JSPLIT, 512, 0, stream>>>(ws2, out);
    }
}